// Round 2
// baseline (207.667 us; speedup 1.0000x reference)
//
#include <hip/hip_runtime.h>
#include <hip/hip_bf16.h>

#define Bsz 4
#define Ssz 2048
#define Dsz 512
#define Hsz 8
#define DKsz 64

typedef __bf16 bf16x8 __attribute__((ext_vector_type(8)));
typedef float f32x4 __attribute__((ext_vector_type(4)));

__device__ inline bf16x8 cvt_bf16x8(const float4& a, const float4& b) {
    bf16x8 r;
    r[0] = (__bf16)a.x; r[1] = (__bf16)a.y; r[2] = (__bf16)a.z; r[3] = (__bf16)a.w;
    r[4] = (__bf16)b.x; r[5] = (__bf16)b.y; r[6] = (__bf16)b.z; r[7] = (__bf16)b.w;
    return r;
}

// y = x @ W^T, 128x128 tile, 4 waves each computing a 64x64 sub-tile.
// Q pre-scaled by 0.125*log2(e) (softmax scale folded, exp -> exp2).
// Q,K -> bf16 [B,H,S,DK]; V -> bf16 [B,H,DK,S] (transposed).
__global__ __launch_bounds__(256) void qkv_proj_kernel(
    const float* __restrict__ x, const float* __restrict__ Wq,
    const float* __restrict__ Wk, const float* __restrict__ Wv,
    __bf16* __restrict__ Qo, __bf16* __restrict__ Ko, __bf16* __restrict__ Vo)
{
    __shared__ __bf16 xs[128][72];   // +8 pad keeps 16B align, kills bank conflicts
    __shared__ __bf16 wsh[128][72];

    const int tid  = threadIdx.x;
    const int lane = tid & 63;
    const int wave = tid >> 6;
    const int quad = lane >> 4;
    const int l16  = lane & 15;
    const int wm   = (wave & 1) * 64;
    const int wn   = (wave >> 1) * 64;

    const int tm = blockIdx.x * 128;
    const int tn = blockIdx.y * 128;
    const int which = blockIdx.z;             // 0=Q 1=K 2=V
    const float* W = (which == 0) ? Wq : (which == 1) ? Wk : Wv;

    const int srow = tid >> 1;                // 0..127
    const int scol = (tid & 1) * 32;          // 0 or 32 (floats)

    f32x4 acc[4][4];
    #pragma unroll
    for (int i = 0; i < 4; ++i)
        #pragma unroll
        for (int j = 0; j < 4; ++j) acc[i][j] = (f32x4){0.f, 0.f, 0.f, 0.f};

    for (int k0 = 0; k0 < Dsz; k0 += 64) {
        const float4* xr = (const float4*)(x + (size_t)(tm + srow) * Dsz + k0 + scol);
        const float4* wr = (const float4*)(W + (size_t)(tn + srow) * Dsz + k0 + scol);
        float4 xv[8], wv[8];
        #pragma unroll
        for (int i = 0; i < 8; ++i) { xv[i] = xr[i]; wv[i] = wr[i]; }
        #pragma unroll
        for (int i = 0; i < 4; ++i) {
            *(bf16x8*)&xs[srow][scol + 8 * i]  = cvt_bf16x8(xv[2 * i], xv[2 * i + 1]);
            *(bf16x8*)&wsh[srow][scol + 8 * i] = cvt_bf16x8(wv[2 * i], wv[2 * i + 1]);
        }
        __syncthreads();

        #pragma unroll
        for (int kk = 0; kk < 2; ++kk) {
            bf16x8 a[4], b[4];
            #pragma unroll
            for (int mi = 0; mi < 4; ++mi)
                a[mi] = *(const bf16x8*)&xs[wm + mi * 16 + l16][kk * 32 + quad * 8];
            #pragma unroll
            for (int ni = 0; ni < 4; ++ni)
                b[ni] = *(const bf16x8*)&wsh[wn + ni * 16 + l16][kk * 32 + quad * 8];
            #pragma unroll
            for (int mi = 0; mi < 4; ++mi)
                #pragma unroll
                for (int ni = 0; ni < 4; ++ni)
                    acc[mi][ni] = __builtin_amdgcn_mfma_f32_16x16x32_bf16(
                        a[mi], b[ni], acc[mi][ni], 0, 0, 0);
        }
        __syncthreads();
    }

    const float qscale = 0.125f * 1.44269504088896340736f;

    // C/D layout: col = l16, row = quad*4 + r
    #pragma unroll
    for (int ni = 0; ni < 4; ++ni) {
        const int n = tn + wn + ni * 16 + l16;
        const int h = n >> 6, d = n & 63;
        #pragma unroll
        for (int mi = 0; mi < 4; ++mi) {
            #pragma unroll
            for (int r = 0; r < 4; ++r) {
                const int m = tm + wm + mi * 16 + quad * 4 + r;
                const int b = m >> 11, s = m & (Ssz - 1);
                const float v = acc[mi][ni][r];
                if (which == 0)
                    Qo[((((size_t)b * Hsz + h) * Ssz + s) << 6) + d] = (__bf16)(v * qscale);
                else if (which == 1)
                    Ko[((((size_t)b * Hsz + h) * Ssz + s) << 6) + d] = (__bf16)v;
                else
                    Vo[(((size_t)b * Hsz + h) * DKsz + d) * Ssz + s] = (__bf16)v;
            }
        }
    }
}

// Flash-style attention, plain exp2 (scale folded into Q), no max-subtraction.
// Block: 4 waves, 128 q-rows of one (b,h): each wave owns two 16-row q-subtiles.
// Row sums computed by an extra MFMA against a ones fragment (replicated over l16).
__global__ __launch_bounds__(256) void attn_kernel(
    const __bf16* __restrict__ Q, const __bf16* __restrict__ K,
    const __bf16* __restrict__ VT, float* __restrict__ out)
{
    __shared__ __bf16 ks[64][72];        // K[s_local][dk]
    __shared__ __bf16 vs[64][72];        // V^T[dk][s_local]
    __shared__ __bf16 ps[4][2][16][72];  // per-wave, per-qsub P tile (C -> A layout)

    const int tid  = threadIdx.x;
    const int lane = tid & 63;
    const int wave = tid >> 6;
    const int quad = lane >> 4;
    const int l16  = lane & 15;

    const int qt = blockIdx.x;           // 128-row q tile (16 tiles)
    const int bh = blockIdx.y;
    const int b  = bh >> 3;
    const int h  = bh & 7;

    const __bf16* Qb = Q  + (size_t)bh * Ssz * DKsz;
    const __bf16* Kb = K  + (size_t)bh * Ssz * DKsz;
    const __bf16* Vb = VT + (size_t)bh * DKsz * Ssz;

    bf16x8 qf[2][2];
    #pragma unroll
    for (int qs = 0; qs < 2; ++qs) {
        const __bf16* qrow = Qb + (size_t)(qt * 128 + qs * 64 + wave * 16 + l16) * DKsz;
        qf[qs][0] = *(const bf16x8*)(qrow + quad * 8);
        qf[qs][1] = *(const bf16x8*)(qrow + 32 + quad * 8);
    }

    bf16x8 ones;
    #pragma unroll
    for (int i = 0; i < 8; ++i) ones[i] = (__bf16)1.0f;

    f32x4 oacc[2][4];
    #pragma unroll
    for (int qs = 0; qs < 2; ++qs)
        #pragma unroll
        for (int i = 0; i < 4; ++i) oacc[qs][i] = (f32x4){0.f, 0.f, 0.f, 0.f};
    f32x4 lacc[2] = {(f32x4){0.f, 0.f, 0.f, 0.f}, (f32x4){0.f, 0.f, 0.f, 0.f}};

    const int srow = tid >> 2;           // 0..63
    const int sc   = (tid & 3) * 8;      // 0,8,16,24

    for (int kb = 0; kb < Ssz; kb += 64) {
        const __bf16* krow = Kb + (size_t)(kb + srow) * DKsz;
        const __bf16* vrow = Vb + (size_t)srow * Ssz + kb;
        bf16x8 k0 = *(const bf16x8*)(krow + sc);
        bf16x8 k1 = *(const bf16x8*)(krow + 32 + sc);
        bf16x8 v0 = *(const bf16x8*)(vrow + sc);
        bf16x8 v1 = *(const bf16x8*)(vrow + 32 + sc);
        *(bf16x8*)&ks[srow][sc]      = k0;
        *(bf16x8*)&ks[srow][32 + sc] = k1;
        *(bf16x8*)&vs[srow][sc]      = v0;
        *(bf16x8*)&vs[srow][32 + sc] = v1;
        __syncthreads();

        #pragma unroll
        for (int qs = 0; qs < 2; ++qs) {
            // S = Q K^T ; P = exp2(S); stash P in per-wave LDS (no barrier needed)
            #pragma unroll
            for (int ns = 0; ns < 4; ++ns) {
                f32x4 sacc = (f32x4){0.f, 0.f, 0.f, 0.f};
                #pragma unroll
                for (int kk = 0; kk < 2; ++kk) {
                    bf16x8 bfr = *(const bf16x8*)&ks[ns * 16 + l16][kk * 32 + quad * 8];
                    sacc = __builtin_amdgcn_mfma_f32_16x16x32_bf16(qf[qs][kk], bfr, sacc, 0, 0, 0);
                }
                #pragma unroll
                for (int r = 0; r < 4; ++r)
                    ps[wave][qs][quad * 4 + r][ns * 16 + l16] =
                        (__bf16)__builtin_amdgcn_exp2f(sacc[r]);
            }

            // O += P V ; row-sum += P * ones (replicated over l16)
            #pragma unroll
            for (int kk = 0; kk < 2; ++kk) {
                bf16x8 af = *(const bf16x8*)&ps[wave][qs][l16][kk * 32 + quad * 8];
                #pragma unroll
                for (int ns = 0; ns < 4; ++ns)
                    oacc[qs][ns] = __builtin_amdgcn_mfma_f32_16x16x32_bf16(
                        af, *(const bf16x8*)&vs[ns * 16 + l16][kk * 32 + quad * 8],
                        oacc[qs][ns], 0, 0, 0);
                lacc[qs] = __builtin_amdgcn_mfma_f32_16x16x32_bf16(af, ones, lacc[qs], 0, 0, 0);
            }
        }
        __syncthreads();
    }

    #pragma unroll
    for (int qs = 0; qs < 2; ++qs) {
        float linv[4];
        #pragma unroll
        for (int r = 0; r < 4; ++r) linv[r] = 1.f / (lacc[qs][r] + 1e-8f);
        #pragma unroll
        for (int ns = 0; ns < 4; ++ns) {
            const int d = ns * 16 + l16;
            #pragma unroll
            for (int r = 0; r < 4; ++r) {
                const int s = qt * 128 + qs * 64 + wave * 16 + quad * 4 + r;
                out[((size_t)b * Ssz + s) * Dsz + h * DKsz + d] = oacc[qs][ns][r] * linv[r];
            }
        }
    }
}

extern "C" void kernel_launch(void* const* d_in, const int* in_sizes, int n_in,
                              void* d_out, int out_size, void* d_ws, size_t ws_size,
                              hipStream_t stream) {
    const float* x  = (const float*)d_in[0];
    const float* Wq = (const float*)d_in[1];
    const float* Wk = (const float*)d_in[2];
    const float* Wv = (const float*)d_in[3];
    float* out = (float*)d_out;

    const size_t per = (size_t)Bsz * Hsz * Ssz * DKsz;  // 4M elements each
    __bf16* Qw = (__bf16*)d_ws;
    __bf16* Kw = Qw + per;
    __bf16* Vw = Kw + per;

    qkv_proj_kernel<<<dim3((Bsz * Ssz) / 128, Dsz / 128, 3), 256, 0, stream>>>(
        x, Wq, Wk, Wv, Qw, Kw, Vw);
    attn_kernel<<<dim3(Ssz / 128, Bsz * Hsz), 256, 0, stream>>>(Qw, Kw, Vw, out);
}

// Round 3
// 152.168 us; speedup vs baseline: 1.3647x; 1.3647x over previous
//
#include <hip/hip_runtime.h>
#include <hip/hip_bf16.h>

#define Bsz 4
#define Ssz 2048
#define Dsz 512
#define Hsz 8
#define DKsz 64

typedef __bf16 bf16x8 __attribute__((ext_vector_type(8)));
typedef float f32x4 __attribute__((ext_vector_type(4)));

// ---------------------------------------------------------------------------
// cvt kernel: x (4.19M fp32) and Wq|Wk|Wv (3 x 262144 fp32) -> bf16 in ws.
// float4-granular; 4864 blocks x 256 thr x 1 float4 = 1,245,184 exactly.
__global__ __launch_bounds__(256) void cvt_kernel(
    const float* __restrict__ x, const float* __restrict__ Wq,
    const float* __restrict__ Wk, const float* __restrict__ Wv,
    __bf16* __restrict__ xb, __bf16* __restrict__ Wb)
{
    const int i = blockIdx.x * 256 + threadIdx.x;   // float4 index
    const int XN4 = (Bsz * Ssz * Dsz) / 4;          // 1,048,576
    const float* src;
    __bf16* dst;
    int off;
    if (i < XN4) {
        src = x; dst = xb; off = i;
    } else {
        int j = i - XN4;                             // 0 .. 196607
        int w = j >> 16;                             // 0,1,2
        off = j & 65535;
        src = (w == 0) ? Wq : (w == 1) ? Wk : Wv;
        dst = Wb + (size_t)w * (Dsz * Dsz);
    }
    float4 v = ((const float4*)src)[off];
    __bf16 o[4] = {(__bf16)v.x, (__bf16)v.y, (__bf16)v.z, (__bf16)v.w};
    *(uint2*)(dst + (size_t)off * 4) = *(uint2*)o;
}

// ---------------------------------------------------------------------------
// y = x @ W^T, 128x128 tile, bf16 inputs (pre-converted), register-prefetch
// staging. Q pre-scaled by 0.125*log2(e). Q,K -> [B,H,S,DK]; V -> [B,H,DK,S]
// via operand swap (A=W-tile, B=x-tile => C = V^T, coalesced stores).
__global__ __launch_bounds__(256) void qkv_proj_kernel(
    const __bf16* __restrict__ xb, const __bf16* __restrict__ Wb,
    __bf16* __restrict__ Qo, __bf16* __restrict__ Ko, __bf16* __restrict__ Vo)
{
    __shared__ __bf16 xs[128][72];
    __shared__ __bf16 wsh[128][72];

    const int tid  = threadIdx.x;
    const int lane = tid & 63;
    const int wave = tid >> 6;
    const int quad = lane >> 4;
    const int l16  = lane & 15;
    const int wm   = (wave & 1) * 64;
    const int wn   = (wave >> 1) * 64;

    const int tm = blockIdx.x * 128;
    const int tn = blockIdx.y * 128;
    const int which = blockIdx.z;             // 0=Q 1=K 2=V
    const __bf16* W = Wb + (size_t)which * (Dsz * Dsz);

    const int srow = tid >> 1;                // 0..127
    const int scol = (tid & 1) * 32;          // 0 or 32 (elems)

    f32x4 acc[4][4];
    #pragma unroll
    for (int i = 0; i < 4; ++i)
        #pragma unroll
        for (int j = 0; j < 4; ++j) acc[i][j] = (f32x4){0.f, 0.f, 0.f, 0.f};

    const __bf16* xrow = xb + (size_t)(tm + srow) * Dsz + scol;
    const __bf16* wrow = W  + (size_t)(tn + srow) * Dsz + scol;

    bf16x8 px[4], pw[4];
    #pragma unroll
    for (int i = 0; i < 4; ++i) {
        px[i] = *(const bf16x8*)(xrow + 8 * i);
        pw[i] = *(const bf16x8*)(wrow + 8 * i);
    }

    const __bf16 (*Ash)[72] = (which == 2) ? wsh : xs;
    const __bf16 (*Bsh)[72] = (which == 2) ? xs : wsh;

    for (int k0 = 0; k0 < Dsz; k0 += 64) {
        __syncthreads();   // previous tile fully consumed
        #pragma unroll
        for (int i = 0; i < 4; ++i) {
            *(bf16x8*)&xs[srow][scol + 8 * i]  = px[i];
            *(bf16x8*)&wsh[srow][scol + 8 * i] = pw[i];
        }
        __syncthreads();
        if (k0 + 64 < Dsz) {   // prefetch next k-tile; drains during compute
            #pragma unroll
            for (int i = 0; i < 4; ++i) {
                px[i] = *(const bf16x8*)(xrow + k0 + 64 + 8 * i);
                pw[i] = *(const bf16x8*)(wrow + k0 + 64 + 8 * i);
            }
        }

        #pragma unroll
        for (int kk = 0; kk < 2; ++kk) {
            bf16x8 a[4], b[4];
            #pragma unroll
            for (int mi = 0; mi < 4; ++mi)
                a[mi] = *(const bf16x8*)&Ash[wm + mi * 16 + l16][kk * 32 + quad * 8];
            #pragma unroll
            for (int ni = 0; ni < 4; ++ni)
                b[ni] = *(const bf16x8*)&Bsh[wn + ni * 16 + l16][kk * 32 + quad * 8];
            #pragma unroll
            for (int mi = 0; mi < 4; ++mi)
                #pragma unroll
                for (int ni = 0; ni < 4; ++ni)
                    acc[mi][ni] = __builtin_amdgcn_mfma_f32_16x16x32_bf16(
                        a[mi], b[ni], acc[mi][ni], 0, 0, 0);
        }
    }

    const float qscale = 0.125f * 1.44269504088896340736f;

    if (which != 2) {
        // C rows = x-rows (m), cols = W-rows (n). col=l16, row=quad*4+r.
        #pragma unroll
        for (int ni = 0; ni < 4; ++ni) {
            const int n = tn + wn + ni * 16 + l16;
            const int h = n >> 6, d = n & 63;
            #pragma unroll
            for (int mi = 0; mi < 4; ++mi) {
                #pragma unroll
                for (int r = 0; r < 4; ++r) {
                    const int m = tm + wm + mi * 16 + quad * 4 + r;
                    const int b = m >> 11, s = m & (Ssz - 1);
                    const float v = acc[mi][ni][r];
                    if (which == 0)
                        Qo[((((size_t)b * Hsz + h) * Ssz + s) << 6) + d] = (__bf16)(v * qscale);
                    else
                        Ko[((((size_t)b * Hsz + h) * Ssz + s) << 6) + d] = (__bf16)v;
                }
            }
        }
    } else {
        // C rows = W-rows (e), cols = x-rows (s): C = V^T tile, coalesced in s.
        #pragma unroll
        for (int mi = 0; mi < 4; ++mi) {
            #pragma unroll
            for (int r = 0; r < 4; ++r) {
                const int e = tn + wm + mi * 16 + quad * 4 + r;
                const int h = e >> 6, d = e & 63;
                #pragma unroll
                for (int ni = 0; ni < 4; ++ni) {
                    const int sx = tm + wn + ni * 16 + l16;
                    const int b = sx >> 11, s = sx & (Ssz - 1);
                    Vo[(((size_t)b * Hsz + h) * DKsz + d) * Ssz + s] = (__bf16)acc[mi][ni][r];
                }
            }
        }
    }
}

// ---------------------------------------------------------------------------
// Flash-style attention, exp2 (scale folded into Q), no max-subtraction.
// Block: 4 waves, 128 q-rows of one (b,h); each wave: 2 x 16-row q-subtiles.
// K/V frags register-cached (read once per k-tile); next tile register-
// prefetched; grid swizzled so all q-blocks of a bh share one XCD's L2.
__global__ __launch_bounds__(256, 2) void attn_kernel(
    const __bf16* __restrict__ Q, const __bf16* __restrict__ K,
    const __bf16* __restrict__ VT, float* __restrict__ out)
{
    __shared__ __bf16 ks[64][72];        // K[s_local][dk]
    __shared__ __bf16 vs[64][72];        // V^T[dk][s_local]
    __shared__ __bf16 ps[4][2][16][72];  // per-wave,per-qsub P (C -> A layout)

    const int tid  = threadIdx.x;
    const int lane = tid & 63;
    const int wave = tid >> 6;
    const int quad = lane >> 4;
    const int l16  = lane & 15;

    const int bh = blockIdx.x;           // x = bh: 16 q-blocks of a bh on one XCD
    const int qt = blockIdx.y;
    const int b  = bh >> 3;
    const int h  = bh & 7;

    const __bf16* Qb = Q  + (size_t)bh * Ssz * DKsz;
    const __bf16* Kb = K  + (size_t)bh * Ssz * DKsz;
    const __bf16* Vb = VT + (size_t)bh * DKsz * Ssz;

    bf16x8 qf[2][2];
    #pragma unroll
    for (int qs = 0; qs < 2; ++qs) {
        const __bf16* qrow = Qb + (size_t)(qt * 128 + qs * 64 + wave * 16 + l16) * DKsz;
        qf[qs][0] = *(const bf16x8*)(qrow + quad * 8);
        qf[qs][1] = *(const bf16x8*)(qrow + 32 + quad * 8);
    }

    bf16x8 ones;
    #pragma unroll
    for (int i = 0; i < 8; ++i) ones[i] = (__bf16)1.0f;

    f32x4 oacc[2][4];
    #pragma unroll
    for (int qs = 0; qs < 2; ++qs)
        #pragma unroll
        for (int i = 0; i < 4; ++i) oacc[qs][i] = (f32x4){0.f, 0.f, 0.f, 0.f};
    f32x4 lacc[2] = {(f32x4){0.f, 0.f, 0.f, 0.f}, (f32x4){0.f, 0.f, 0.f, 0.f}};

    const int srow = tid >> 2;           // 0..63
    const int sc   = (tid & 3) * 8;      // 0,8,16,24

    const __bf16* krow = Kb + (size_t)srow * DKsz + sc;
    const __bf16* vrow = Vb + (size_t)srow * Ssz + sc;

    bf16x8 pk0 = *(const bf16x8*)(krow);
    bf16x8 pk1 = *(const bf16x8*)(krow + 32);
    bf16x8 pv0 = *(const bf16x8*)(vrow);
    bf16x8 pv1 = *(const bf16x8*)(vrow + 32);

    for (int kb = 0; kb < Ssz; kb += 64) {
        __syncthreads();                 // previous tile consumers done
        *(bf16x8*)&ks[srow][sc]      = pk0;
        *(bf16x8*)&ks[srow][32 + sc] = pk1;
        *(bf16x8*)&vs[srow][sc]      = pv0;
        *(bf16x8*)&vs[srow][32 + sc] = pv1;
        __syncthreads();

        if (kb + 64 < Ssz) {             // prefetch next K/V tile into regs
            pk0 = *(const bf16x8*)(krow + (size_t)(kb + 64) * DKsz);
            pk1 = *(const bf16x8*)(krow + (size_t)(kb + 64) * DKsz + 32);
            pv0 = *(const bf16x8*)(vrow + kb + 64);
            pv1 = *(const bf16x8*)(vrow + kb + 96);
        }

        // read each K/V fragment exactly once per k-tile
        bf16x8 kf[2][4], vf[2][4];
        #pragma unroll
        for (int kk = 0; kk < 2; ++kk)
            #pragma unroll
            for (int ns = 0; ns < 4; ++ns) {
                kf[kk][ns] = *(const bf16x8*)&ks[ns * 16 + l16][kk * 32 + quad * 8];
                vf[kk][ns] = *(const bf16x8*)&vs[ns * 16 + l16][kk * 32 + quad * 8];
            }

        #pragma unroll
        for (int qs = 0; qs < 2; ++qs) {
            f32x4 sacc[4];
            #pragma unroll
            for (int ns = 0; ns < 4; ++ns) {
                sacc[ns] = (f32x4){0.f, 0.f, 0.f, 0.f};
                sacc[ns] = __builtin_amdgcn_mfma_f32_16x16x32_bf16(qf[qs][0], kf[0][ns], sacc[ns], 0, 0, 0);
                sacc[ns] = __builtin_amdgcn_mfma_f32_16x16x32_bf16(qf[qs][1], kf[1][ns], sacc[ns], 0, 0, 0);
            }
            #pragma unroll
            for (int ns = 0; ns < 4; ++ns)
                #pragma unroll
                for (int r = 0; r < 4; ++r)
                    ps[wave][qs][quad * 4 + r][ns * 16 + l16] =
                        (__bf16)__builtin_amdgcn_exp2f(sacc[ns][r]);

            bf16x8 af0 = *(const bf16x8*)&ps[wave][qs][l16][quad * 8];
            bf16x8 af1 = *(const bf16x8*)&ps[wave][qs][l16][32 + quad * 8];
            #pragma unroll
            for (int ns = 0; ns < 4; ++ns) {
                oacc[qs][ns] = __builtin_amdgcn_mfma_f32_16x16x32_bf16(af0, vf[0][ns], oacc[qs][ns], 0, 0, 0);
                oacc[qs][ns] = __builtin_amdgcn_mfma_f32_16x16x32_bf16(af1, vf[1][ns], oacc[qs][ns], 0, 0, 0);
            }
            lacc[qs] = __builtin_amdgcn_mfma_f32_16x16x32_bf16(af0, ones, lacc[qs], 0, 0, 0);
            lacc[qs] = __builtin_amdgcn_mfma_f32_16x16x32_bf16(af1, ones, lacc[qs], 0, 0, 0);
        }
    }

    #pragma unroll
    for (int qs = 0; qs < 2; ++qs) {
        float linv[4];
        #pragma unroll
        for (int r = 0; r < 4; ++r) linv[r] = 1.f / (lacc[qs][r] + 1e-8f);
        #pragma unroll
        for (int ns = 0; ns < 4; ++ns) {
            const int d = ns * 16 + l16;
            #pragma unroll
            for (int r = 0; r < 4; ++r) {
                const int s = qt * 128 + qs * 64 + wave * 16 + quad * 4 + r;
                out[((size_t)b * Ssz + s) * Dsz + h * DKsz + d] = oacc[qs][ns][r] * linv[r];
            }
        }
    }
}

extern "C" void kernel_launch(void* const* d_in, const int* in_sizes, int n_in,
                              void* d_out, int out_size, void* d_ws, size_t ws_size,
                              hipStream_t stream) {
    const float* x  = (const float*)d_in[0];
    const float* Wq = (const float*)d_in[1];
    const float* Wk = (const float*)d_in[2];
    const float* Wv = (const float*)d_in[3];
    float* out = (float*)d_out;

    const size_t per = (size_t)Bsz * Hsz * Ssz * DKsz;  // 4,194,304 elems
    __bf16* Qw  = (__bf16*)d_ws;
    __bf16* Kw  = Qw + per;
    __bf16* VTw = Kw + per;
    __bf16* xb  = VTw + per;
    __bf16* Wb  = xb + per;                              // 786,432 elems

    cvt_kernel<<<4864, 256, 0, stream>>>(x, Wq, Wk, Wv, xb, Wb);
    qkv_proj_kernel<<<dim3((Bsz * Ssz) / 128, Dsz / 128, 3), 256, 0, stream>>>(
        xb, Wb, Qw, Kw, VTw);
    attn_kernel<<<dim3(Bsz * Hsz, Ssz / 128), 256, 0, stream>>>(Qw, Kw, VTw, out);
}